// Round 3
// baseline (138.607 us; speedup 1.0000x reference)
//
#include <hip/hip_runtime.h>

#define NNODES 10000
#define NEDGES 4096
#define INF 300
#define OUTF 150
#define KCAT (2 * INF)              // combined K = 600: [ef*h | h] @ [W ; B]
#define EPB 32                      // edges per block
#define NGROUPS (NEDGES / EPB)      // 128
#define SPLITK 15                   // chunks over combined K
#define KCHUNK (KCAT / SPLITK)      // 40 (multiple of 4; 300 % 4 == 0 so W/B straddle is float4-clean)
#define ETHREADS 192                // lanes 0..149 compute, 150..181 counts

// ws layout (floats): sums[NNODES*OUTF] | cnts[NNODES] | wcat[KCAT*OUTF]
#define SUMS_N   (NNODES * OUTF)
#define ZERO_N   (SUMS_N + NNODES)
#define WCAT_N   (KCAT * OUTF)

__global__ __launch_bounds__(256) void prep_kernel(
    const float* __restrict__ W, const float* __restrict__ B,
    float* __restrict__ zero_region, float* __restrict__ wcat)
{
    const int idx = blockIdx.x * blockDim.x + threadIdx.x;
    if (idx < ZERO_N) {
        zero_region[idx] = 0.f;                    // sums + cnts
    } else if (idx < ZERO_N + WCAT_N) {
        const int j = idx - ZERO_N;
        wcat[j] = (j < INF * OUTF) ? W[j] : B[j - INF * OUTF];
    }
}

__global__ __launch_bounds__(ETHREADS) void edge_msg_kernel(
    const float* __restrict__ feat, const float* __restrict__ efeat,
    const float* __restrict__ wcat,
    const int* __restrict__ src, const int* __restrict__ dst,
    float* __restrict__ sums, float* __restrict__ cnts)
{
    __shared__ float hA[EPB][KCHUNK];   // staged A-chunk: [ef*h | h] slice
    __shared__ float s_ef[EPB];
    __shared__ int   s_dst[EPB];
    __shared__ int   s_src[EPB];

    const int tid = threadIdx.x;
    const int kc  = blockIdx.x / NGROUPS;        // consecutive blocks share kc -> Wcat chunk L2-shared
    const int grp = blockIdx.x - kc * NGROUPS;
    const int e0  = grp * EPB;
    const int k0  = kc * KCHUNK;                 // combined-K offset

    if (tid < EPB) {
        const int e = e0 + tid;
        s_src[tid] = src[e];
        s_dst[tid] = dst[e];
        s_ef[tid]  = efeat[e];
    }
    __syncthreads();

    // Stage this K-chunk of the 32 gathered rows as float4 (10 float4/row).
    for (int q = tid; q < EPB * (KCHUNK / 4); q += ETHREADS) {
        const int el = q / (KCHUNK / 4);
        const int j4 = q - el * (KCHUNK / 4);
        const int gi = k0 + 4 * j4;              // combined index
        const float* rp = feat + (size_t)s_src[el] * INF;
        float4 v;
        if (gi < INF) {                          // ef-scaled half (feeds W rows)
            v = *(const float4*)(rp + gi);
            const float ef = s_ef[el];
            v.x *= ef; v.y *= ef; v.z *= ef; v.w *= ef;
        } else {                                 // raw half (feeds B rows)
            v = *(const float4*)(rp + gi - INF);
        }
        *(float4*)&hA[el][4 * j4] = v;
    }
    __syncthreads();

    if (tid < OUTF) {
        float acc[EPB];
        #pragma unroll
        for (int e = 0; e < EPB; ++e) acc[e] = 0.f;

        const float* Wc = wcat + (size_t)k0 * OUTF + tid;   // column o = tid
        for (int i4 = 0; i4 < KCHUNK; i4 += 4) {
            const float w0 = Wc[(size_t)(i4 + 0) * OUTF];   // coalesced, L2-hit
            const float w1 = Wc[(size_t)(i4 + 1) * OUTF];
            const float w2 = Wc[(size_t)(i4 + 2) * OUTF];
            const float w3 = Wc[(size_t)(i4 + 3) * OUTF];
            #pragma unroll
            for (int e = 0; e < EPB; ++e) {
                const float4 h = *(const float4*)&hA[e][i4]; // broadcast b128, no conflict
                acc[e] = fmaf(h.w, w3, fmaf(h.z, w2, fmaf(h.y, w1, fmaf(h.x, w0, acc[e]))));
            }
        }
        #pragma unroll
        for (int e = 0; e < EPB; ++e)
            atomicAdd(&sums[(size_t)s_dst[e] * OUTF + tid], acc[e]);
    } else if (kc == 0 && tid < OUTF + EPB) {
        atomicAdd(&cnts[s_dst[tid - OUTF]], 1.0f);   // count each edge once
    }
}

__global__ __launch_bounds__(256) void finalize_kernel(
    const float* __restrict__ sums, const float* __restrict__ cnts,
    const float* __restrict__ bias, float* __restrict__ out)
{
    const int idx = blockIdx.x * blockDim.x + threadIdx.x;
    if (idx < SUMS_N) {
        const int n = idx / OUTF;
        const int o = idx - n * OUTF;
        const float c = cnts[n];
        const float m = sums[idx] / fmaxf(c, 1.0f);
        const float v = m + bias[o];
        out[idx] = v > 0.f ? v : 0.f;
    }
}

extern "C" void kernel_launch(void* const* d_in, const int* in_sizes, int n_in,
                              void* d_out, int out_size, void* d_ws, size_t ws_size,
                              hipStream_t stream) {
    const float* feat  = (const float*)d_in[0];
    const float* efeat = (const float*)d_in[1];
    const float* W     = (const float*)d_in[2];
    const float* B     = (const float*)d_in[3];
    const float* bias  = (const float*)d_in[4];
    const int*   src   = (const int*)d_in[5];
    const int*   dst   = (const int*)d_in[6];
    float* out  = (float*)d_out;

    float* sums = (float*)d_ws;
    float* cnts = sums + SUMS_N;
    float* wcat = sums + ZERO_N;

    const int prep_total = ZERO_N + WCAT_N;
    prep_kernel<<<(prep_total + 255) / 256, 256, 0, stream>>>(W, B, sums, wcat);

    edge_msg_kernel<<<NGROUPS * SPLITK, ETHREADS, 0, stream>>>(
        feat, efeat, wcat, src, dst, sums, cnts);

    finalize_kernel<<<(SUMS_N + 255) / 256, 256, 0, stream>>>(sums, cnts, bias, out);
}